// Round 15
// baseline (145.315 us; speedup 1.0000x reference)
//
#include <hip/hip_runtime.h>
#include <stdint.h>

typedef short s16x8 __attribute__((ext_vector_type(8)));
typedef float f32x4 __attribute__((ext_vector_type(4)));
typedef unsigned int u32x4 __attribute__((ext_vector_type(4)));

#define AS1 __attribute__((address_space(1)))
#define AS3 __attribute__((address_space(3)))

static constexpr int Bc = 2, Tc = 2048, NXc = 1024, Hc = 16;
static constexpr float NEGC = -1e9f;
static constexpr float L2E = 1.44269504088896340736f;  // log2(e)
static constexpr float LN2 = 0.69314718055994530942f;  // 1/log2(e)

static __device__ __forceinline__ unsigned short f2bf(float f) {
  uint32_t u = __builtin_bit_cast(uint32_t, f);
  u += 0x7fffu + ((u >> 16) & 1u);
  return (unsigned short)(u >> 16);
}

static __device__ __forceinline__ float exp2fast(float x) {
  return __builtin_amdgcn_exp2f(x);  // v_exp_f32: D = 2^S0
}

static __device__ __forceinline__ uint32_t cvt_pk_bf16(float lo, float hi) {
  uint32_t r;
  asm("v_cvt_pk_bf16_f32 %0, %1, %2" : "=v"(r) : "v"(lo), "v"(hi));
  return r;
}

static __device__ __forceinline__ void gload_lds16(const void* g, void* l) {
  __builtin_amdgcn_global_load_lds((const AS1 uint32_t*)g, (AS3 uint32_t*)l, 16, 0, 0);
}

// ---------------- fused prep: cvt_x | 3 transposes | tilemask(64x64) ----------------
__global__ __launch_bounds__(256) void k_prep(
    const float* __restrict__ x, unsigned short* __restrict__ xb,
    const float* __restrict__ w_attn, unsigned short* __restrict__ wattnT,
    const float* __restrict__ w_proj, const float* __restrict__ w_proj1,
    unsigned short* __restrict__ wcatT,
    const float* __restrict__ adj, unsigned char* __restrict__ tm) {
  __shared__ float tile[32][33];
  __shared__ int s_any, s_all;
  const int bid = blockIdx.x;
  const int t = threadIdx.x;

  if (bid < 4096) {  // x -> bf16
    int i = bid * 256 + t;
    float4 v = ((const float4*)x)[i];
    uint32_t lo = (uint32_t)f2bf(v.x) | ((uint32_t)f2bf(v.y) << 16);
    uint32_t hi = (uint32_t)f2bf(v.z) | ((uint32_t)f2bf(v.w) << 16);
    ((uint2*)xb)[i] = make_uint2(lo, hi);
    return;
  }
  if (bid < 9216) {  // f32 [K][N] -> bf16 [N][dld] transposes
    const float* src; unsigned short* dst;
    int scols, dld, dkoff, n0, k0; float scale;
    if (bid < 7168) {
      int b = bid - 4096; n0 = (b % 96) * 32; k0 = (b / 96) * 32;
      src = w_attn; scols = 3072; dst = wattnT; dld = 1024; dkoff = 0; scale = 1.0f;
    } else if (bid < 8192) {
      int b = bid - 7168; n0 = (b & 31) * 32; k0 = (b >> 5) * 32;
      src = w_proj; scols = 1024; dst = wcatT; dld = 2048; dkoff = 0; scale = 1.0f;
    } else {
      int b = bid - 8192; n0 = (b & 31) * 32; k0 = (b >> 5) * 32;
      // w_proj1 pre-scaled by ln2 cancels the log2e baked into q (exp2 rebasing)
      src = w_proj1; scols = 1024; dst = wcatT; dld = 2048; dkoff = 1024; scale = LN2;
    }
    int tx = t & 31, ty = t >> 5;
#pragma unroll
    for (int r = 0; r < 4; r++)
      tile[ty + r * 8][tx] = src[(size_t)(k0 + ty + r * 8) * scols + n0 + tx];
    __syncthreads();
#pragma unroll
    for (int r = 0; r < 4; r++) {
      int n = n0 + ty + r * 8;
      dst[(size_t)n * dld + dkoff + k0 + tx] = f2bf(tile[tx][ty + r * 8] * scale);
    }
    return;
  }
  {  // adjacency 64x64 tile classifier: 0=skip, 1=mixed, 2=all-ones
    int b = bid - 9216;
    int kt = b & 31, qt = b >> 5;
    bool anyv = false, all1 = true;
#pragma unroll
    for (int i = 0; i < 4; i++) {
      int e = t * 4 + i;
      int row = e >> 4, c4 = e & 15;
      float4 v = *(const float4*)&adj[(size_t)(qt * 64 + row) * Tc + kt * 64 + c4 * 4];
      anyv |= (v.x != 0.f) | (v.y != 0.f) | (v.z != 0.f) | (v.w != 0.f);
      all1 &= (v.x == 1.f) & (v.y == 1.f) & (v.z == 1.f) & (v.w == 1.f);
    }
    if (t == 0) { s_any = 0; s_all = 1; }
    __syncthreads();
    if (anyv) s_any = 1;
    if (!all1) s_all = 0;
    __syncthreads();
    if (t == 0) tm[qt * 32 + kt] = (unsigned char)(s_any ? (s_all ? 2 : 1) : 0);
  }
}

// ---------------- GEMM0: qkv = xb @ wattnT^T + b_attn (m97-structure, BK=32) ------
__global__ __launch_bounds__(256) void k_gemm0(
    const unsigned short* __restrict__ A, int lda,
    const unsigned short* __restrict__ BT, int K,
    const float* __restrict__ bias0, unsigned short* __restrict__ Cb) {
  __shared__ __align__(16) unsigned short As[128 * 32];
  __shared__ __align__(16) unsigned short Bs[128 * 32];
  const int nbx = gridDim.x, nby = gridDim.y;
  const int nwg = nbx * nby;
  int id = blockIdx.y * nbx + blockIdx.x;
  id = (id & 7) * (nwg >> 3) + (id >> 3);  // T1 XCD swizzle (nwg % 8 == 0)
  const int bx = id % nbx;
  const int by = id / nbx;
  const int m0 = by * 128;
  const int n0 = bx * 128;

  const int lane = threadIdx.x & 63;
  const int w = threadIdx.x >> 6;
  const int wr = (w >> 1) * 64;
  const int wc = (w & 1) * 64;
  const int g = lane >> 4, lr = lane & 15;
  const int srow = lane >> 2;
  const int scol = lane & 3;
  f32x4 acc[4][4] = {};

  for (int k0 = 0; k0 < K; k0 += 32) {
    __syncthreads();
#pragma unroll
    for (int i = 0; i < 2; i++) {
      int c = w * 2 + i;
      int row = c * 16 + srow;
      int cs = scol ^ (row & 3);
      gload_lds16(A + (size_t)(m0 + row) * lda + k0 + cs * 8, (void*)(As + c * 512));
      gload_lds16(BT + (size_t)(n0 + row) * K + k0 + cs * 8, (void*)(Bs + c * 512));
    }
    __syncthreads();
    s16x8 af[4], bfr[4];
#pragma unroll
    for (int m = 0; m < 4; m++) {
      int row = wr + m * 16 + lr;
      af[m] = *(const s16x8*)((const char*)As + row * 64 + ((g ^ (row & 3)) * 16));
    }
#pragma unroll
    for (int n = 0; n < 4; n++) {
      int row = wc + n * 16 + lr;
      bfr[n] = *(const s16x8*)((const char*)Bs + row * 64 + ((g ^ (row & 3)) * 16));
    }
#pragma unroll
    for (int m = 0; m < 4; m++)
#pragma unroll
      for (int n = 0; n < 4; n++)
        acc[m][n] = __builtin_amdgcn_mfma_f32_16x16x32_bf16(af[m], bfr[n], acc[m][n], 0, 0, 0);
  }

#pragma unroll
  for (int m = 0; m < 4; m++) {
    int row = m0 + wr + m * 16 + g * 4;
#pragma unroll
    for (int n = 0; n < 4; n++) {
      int col = n0 + wc + n * 16 + lr;
      float bs = bias0[col];
      float sc = (col < NXc) ? L2E : 1.0f;  // pre-scale q for exp2-softmax
#pragma unroll
      for (int jj = 0; jj < 4; jj++)
        Cb[(size_t)(row + jj) * 3072 + col] = f2bf((acc[m][n][jj] + bs) * sc);
    }
  }
}

// ---------------- GEMM1: out = [acat | q] @ wcatT^T + biases (M=64 tile, dbuf) -------
__global__ __launch_bounds__(256) void k_gemm1(
    const unsigned short* __restrict__ A, int lda,    // acat (k < 1024)
    const unsigned short* __restrict__ A2, int lda2,  // qkv cols 0..1023 (k >= 1024)
    const unsigned short* __restrict__ BT,            // [1024][2048]
    const float* __restrict__ bias0, const float* __restrict__ bias1,
    float* __restrict__ Cf) {
  constexpr int K = 2048, ksplit = 1024;
  __shared__ __align__(16) unsigned short As[2][64 * 32];    // 8 KB dbuf
  __shared__ __align__(16) unsigned short Bs[2][128 * 32];   // 16 KB dbuf
  const int nbx = gridDim.x, nby = gridDim.y;
  const int nwg = nbx * nby;
  int id = blockIdx.y * nbx + blockIdx.x;
  id = (id & 7) * (nwg >> 3) + (id >> 3);  // T1 XCD swizzle (512 % 8 == 0)
  const int bx = id % nbx;
  const int by = id / nbx;
  const int m0 = by * 64;
  const int n0 = bx * 128;

  const int tid = threadIdx.x;
  const int lane = tid & 63;
  const int w = tid >> 6;
  const int wr = (w >> 1) * 32;
  const int wc = (w & 1) * 64;
  const int g = lane >> 4, lr = lane & 15;
  const int srow = lane >> 2;
  const int scol = lane & 3;
  const int arow = tid >> 2;
  f32x4 acc[2][4] = {};

  auto stage = [&](int k0, int buf) {
    {
      int acs = (tid & 3) ^ (arow & 3);
      const unsigned short* ap = (k0 < ksplit)
          ? A + (size_t)(m0 + arow) * lda + k0
          : A2 + (size_t)(m0 + arow) * lda2 + (k0 - ksplit);
      gload_lds16(ap + acs * 8, (void*)(&As[buf][0] + w * 512));
    }
#pragma unroll
    for (int i = 0; i < 2; i++) {
      int c = w * 2 + i;
      int row = c * 16 + srow;
      int cs = scol ^ (row & 3);
      gload_lds16(BT + (size_t)(n0 + row) * K + k0 + cs * 8, (void*)(&Bs[buf][0] + c * 512));
    }
  };

  stage(0, 0);
  __syncthreads();

  for (int k0 = 0; k0 < K; k0 += 32) {
    const int cur = (k0 >> 5) & 1;
    if (k0 + 32 < K) stage(k0 + 32, cur ^ 1);
    s16x8 af[2], bfr[4];
#pragma unroll
    for (int m = 0; m < 2; m++) {
      int row = wr + m * 16 + lr;
      af[m] = *(const s16x8*)((const char*)&As[cur][0] + row * 64 + ((g ^ (row & 3)) * 16));
    }
#pragma unroll
    for (int n = 0; n < 4; n++) {
      int row = wc + n * 16 + lr;
      bfr[n] = *(const s16x8*)((const char*)&Bs[cur][0] + row * 64 + ((g ^ (row & 3)) * 16));
    }
#pragma unroll
    for (int m = 0; m < 2; m++)
#pragma unroll
      for (int n = 0; n < 4; n++)
        acc[m][n] = __builtin_amdgcn_mfma_f32_16x16x32_bf16(af[m], bfr[n], acc[m][n], 0, 0, 0);
    __syncthreads();
  }

#pragma unroll
  for (int m = 0; m < 2; m++) {
    int row = m0 + wr + m * 16 + g * 4;
#pragma unroll
    for (int n = 0; n < 4; n++) {
      int col = n0 + wc + n * 16 + lr;
      float bs = bias0[col] + bias1[col];
#pragma unroll
      for (int jj = 0; jj < 4; jj++)
        Cf[(size_t)(row + jj) * NXc + col] = acc[m][n][jj] + bs;
    }
  }
}

// ---------------- flash attention v10: balanced split blocks + additive partials -----
// r14 diagnosis: 1024 blocks = exact chip capacity; no backfill -> runtime = longest
// block (33 tiles). Split each (bh, qt-pair p): blockA = first 17 tiles of qt_hi=31-p;
// blockB = rest of qt_hi (15-p) then all of qt_lo=p (16 total). no-max softmax makes
// partials EXACTLY additive: (oA+oB)/(lA+lB). Both write raw f32 slabs for qt_hi;
// k_combine reduces; blockB writes qt_lo rows directly. 1024 uniform ~17-tile blocks.
__global__ __launch_bounds__(256) void k_attn(
    const unsigned short* __restrict__ qkv,  // [4096][3072] bf16 (q*l2e | k | v)
    const float* __restrict__ adj,           // [2048][2048]
    const unsigned char* __restrict__ tm,    // [32][32] 64x64 tiles
    unsigned short* __restrict__ acat,       // [4096][1024] bf16
    float* __restrict__ o_slab,              // [2 half][2 b][1024 hi-row][1024] f32
    float* __restrict__ l_slab) {            // [2 half][2 b][1024 hi-row][16 h] f32
  __shared__ __align__(16) unsigned short Kb[2][64 * 64];
  __shared__ __align__(16) unsigned short Vt[2][64 * 72];
  __shared__ int s_hi[32], s_lo[32];
  __shared__ int s_nh, s_nl;

  const int bid = blockIdx.x;
  const int half = bid & 1;
  const int bh = (bid >> 1) & 31;
  const int p = bid >> 6;          // 0..15
  const int qt_hi = 31 - p, qt_lo = p;
  const int h = bh & 15;
  const int b = bh >> 4;
  const int tid = threadIdx.x;
  const int lane = tid & 63;
  const int w = tid >> 6;
  const int g = lane >> 4, lr = lane & 15;
  const int sc = tid & 7;
  const int sr = tid >> 3;
  const int kvp = 2 * sr;
  const int prp = (kvp & 32) | (((kvp >> 4) & 1) << 2) | ((kvp & 12) << 1) | (kvp & 3);

  // active-tile lists for both qts (waves 0 and 1)
  if (w < 2) {
    int qt = (w == 0) ? qt_hi : qt_lo;
    int* dst = (w == 0) ? s_hi : s_lo;
    int kt = lane & 31;
    unsigned char v = tm[qt * 32 + kt];
    bool act = (lane < 32) && (v != 0);
    unsigned long long mk = __ballot(act);
    int n = __popcll(mk);
    if (act) {
      int idx = __popcll(mk & ((1ull << lane) - 1));
      dst[idx] = kt | ((int)v << 8);
    }
    if (lane == 0) { if (w == 0) s_nh = n; else s_nl = n; }
  }
  __syncthreads();
  const int nh = s_nh, nl = s_nl;
  const int nA = min(nh, 17);
  const int nhB = nh - nA;
  const int nit = (half == 0) ? nA : (nhB + nl);

  auto item_at = [&](int i) -> int {
    if (half == 0) return s_hi[min(i, nA - 1)];
    if (i < nhB) return s_hi[nA + i];
    return s_lo[min(i - nhB, nl - 1)];
  };

  const unsigned short* kbase = qkv + (size_t)(b * Tc) * 3072 + 1024 + h * 64;
  const unsigned short* vbase = kbase + 1024;

  f32x4 o[4] = {};
  float lrow = 0.f;
  bool switched = (half == 1) && (nhB == 0);
  int cur_q0 = (half == 0 || nhB > 0) ? qt_hi * 64 : qt_lo * 64;

  // raw-partial writer for qt_hi rows (o and l UNNORMALIZED; additive across halves)
  auto write_partial = [&]() {
    size_t rbase = (size_t)(half * 2 + b) * 1024 + (qt_hi * 64 - 1024) + w * 16;
#pragma unroll
    for (int jj = 0; jj < 4; jj++) {
      size_t r = rbase + g * 4 + jj;
#pragma unroll
      for (int nd = 0; nd < 4; nd++)
        o_slab[r * 1024 + h * 64 + nd * 16 + lr] = o[nd][jj];
    }
    if (g == 0) l_slab[(rbase + lr) * 16 + h] = lrow;
  };

  // Q fragments (mfma B-operand: col=q=lr, k=8g+j)
  s16x8 qf0, qf1;
  {
    size_t base = (size_t)(b * Tc + cur_q0 + w * 16 + lr) * 3072 + h * 64 + g * 8;
    qf0 = *(const s16x8*)(qkv + base);
    qf1 = *(const s16x8*)(qkv + base + 32);
  }

  if (nit > 0) {
    // ---- prologue: stage item 0 ----
    {
      int it0 = item_at(0);
      int kt0 = it0 & 255;
      const unsigned short* kb = kbase + (size_t)kt0 * 64 * 3072;
      gload_lds16(kb + (size_t)sr * 3072 + (sc ^ (sr & 7)) * 8, (void*)(&Kb[0][0] + w * 512));
      gload_lds16(kb + (size_t)(sr + 32) * 3072 + (sc ^ (sr & 7)) * 8,
                  (void*)(&Kb[0][0] + 2048 + w * 512));
      const unsigned short* vb = vbase + (size_t)kt0 * 64 * 3072;
      s16x8 v0 = *(const s16x8*)(vb + (size_t)kvp * 3072 + sc * 8);
      s16x8 v1 = *(const s16x8*)(vb + (size_t)(kvp + 1) * 3072 + sc * 8);
      char* vt = (char*)&Vt[0][0];
      int pcol = ((prp + sc * 8) & 63) * 2;
#pragma unroll
      for (int j = 0; j < 8; j++) {
        int d = sc * 8 + j;
        uint32_t pk = (uint32_t)(unsigned short)v0[j] |
                      ((uint32_t)(unsigned short)v1[j] << 16);
        *(uint32_t*)(vt + d * 144 + pcol) = pk;
      }
    }
    __syncthreads();

    for (int i = 0; i < nit; i++) {
      // blockB qt-switch: flush qt_hi partial, reset accum, reload Q for qt_lo.
      // Register/global ops only — barrier structure identical for all waves.
      if (half == 1 && !switched && i == nhB) {
        write_partial();
#pragma unroll
        for (int nd = 0; nd < 4; nd++) o[nd] = f32x4{0.f, 0.f, 0.f, 0.f};
        lrow = 0.f;
        cur_q0 = qt_lo * 64;
        size_t base = (size_t)(b * Tc + cur_q0 + w * 16 + lr) * 3072 + h * 64 + g * 8;
        qf0 = *(const s16x8*)(qkv + base);
        qf1 = *(const s16x8*)(qkv + base + 32);
        switched = true;
      }
      const int cur = i & 1;
      const int it = item_at(i);
      const int kt = it & 255;
      const int tmv = it >> 8;
      const int kv0 = kt * 64;
      const int nxt = item_at(min(i + 1, nit - 1)) & 255;

      // ---- prefetch next tile (K direct-to-LDS, V to regs) ----
      {
        const unsigned short* kb = kbase + (size_t)nxt * 64 * 3072;
        gload_lds16(kb + (size_t)sr * 3072 + (sc ^ (sr & 7)) * 8,
                    (void*)(&Kb[cur ^ 1][0] + w * 512));
        gload_lds16(kb + (size_t)(sr + 32) * 3072 + (sc ^ (sr & 7)) * 8,
                    (void*)(&Kb[cur ^ 1][0] + 2048 + w * 512));
      }
      const unsigned short* vb = vbase + (size_t)nxt * 64 * 3072;
      s16x8 v0 = *(const s16x8*)(vb + (size_t)kvp * 3072 + sc * 8);
      s16x8 v1 = *(const s16x8*)(vb + (size_t)(kvp + 1) * 3072 + sc * 8);

      // ---- S^T = K Q ----
      f32x4 s[4];
      __builtin_amdgcn_s_setprio(1);
#pragma unroll
      for (int n = 0; n < 4; n++) {
        int kvr = n * 16 + lr;
        const char* kr = (const char*)&Kb[cur][0] + kvr * 128;
        s16x8 a0 = *(const s16x8*)(kr + ((g ^ (kvr & 7)) * 16));
        s16x8 a1 = *(const s16x8*)(kr + (((4 + g) ^ (kvr & 7)) * 16));
        f32x4 z = {};
        z = __builtin_amdgcn_mfma_f32_16x16x32_bf16(a0, qf0, z, 0, 0, 0);
        s[n] = __builtin_amdgcn_mfma_f32_16x16x32_bf16(a1, qf1, z, 0, 0, 0);
      }
      __builtin_amdgcn_s_setprio(0);

      if (tmv != 2) {  // w = s*adj + NEG*(1-adj), exact for binary adj
        const float* arow = adj + (size_t)(cur_q0 + w * 16 + lr) * Tc + kv0;
#pragma unroll
        for (int n = 0; n < 4; n++) {
          float4 a = *(const float4*)(arow + n * 16 + 4 * g);
          s[n][0] = a.x * s[n][0] + NEGC * (1.0f - a.x);
          s[n][1] = a.y * s[n][1] + NEGC * (1.0f - a.y);
          s[n][2] = a.z * s[n][2] + NEGC * (1.0f - a.z);
          s[n][3] = a.w * s[n][3] + NEGC * (1.0f - a.w);
        }
      }

      // ---- no-max softmax: P = exp2(s) directly ----
      float ps0 = 0.f, ps1 = 0.f;
#pragma unroll
      for (int n = 0; n < 4; n++) {
        float p0 = exp2fast(s[n][0]), p1 = exp2fast(s[n][1]);
        float p2 = exp2fast(s[n][2]), p3 = exp2fast(s[n][3]);
        s[n][0] = p0; s[n][1] = p1; s[n][2] = p2; s[n][3] = p3;
        ps0 += (p0 + p1); ps1 += (p2 + p3);
      }
      float ps = ps0 + ps1;
      ps += __shfl_xor(ps, 16);
      ps += __shfl_xor(ps, 32);
      lrow += ps;

      // ---- P in registers: sigma-renamed packs ----
      u32x4 pw0, pw1;
      pw0.x = cvt_pk_bf16(s[0][0], s[0][1]);
      pw0.y = cvt_pk_bf16(s[0][2], s[0][3]);
      pw0.z = cvt_pk_bf16(s[1][0], s[1][1]);
      pw0.w = cvt_pk_bf16(s[1][2], s[1][3]);
      pw1.x = cvt_pk_bf16(s[2][0], s[2][1]);
      pw1.y = cvt_pk_bf16(s[2][2], s[2][3]);
      pw1.z = cvt_pk_bf16(s[3][0], s[3][1]);
      pw1.w = cvt_pk_bf16(s[3][2], s[3][3]);
      s16x8 pa0 = __builtin_bit_cast(s16x8, pw0);
      s16x8 pa1 = __builtin_bit_cast(s16x8, pw1);

      __builtin_amdgcn_s_setprio(1);
#pragma unroll
      for (int nd = 0; nd < 4; nd++) {
        int d = nd * 16 + lr;
        const char* vrow = (const char*)&Vt[cur][0] + d * 144;
        int swz = (d >> 3) * 8;
        s16x8 vb0 = *(const s16x8*)(vrow + (((8 * g + swz) & 63) * 2));
        s16x8 vb1 = *(const s16x8*)(vrow + (((32 + 8 * g + swz) & 63) * 2));
        o[nd] = __builtin_amdgcn_mfma_f32_16x16x32_bf16(pa0, vb0, o[nd], 0, 0, 0);
        o[nd] = __builtin_amdgcn_mfma_f32_16x16x32_bf16(pa1, vb1, o[nd], 0, 0, 0);
      }
      __builtin_amdgcn_s_setprio(0);

      // ---- late V^T write for next tile ----
      {
        char* vt = (char*)&Vt[cur ^ 1][0];
        int pcol = ((prp + sc * 8) & 63) * 2;
#pragma unroll
        for (int j = 0; j < 8; j++) {
          int d = sc * 8 + j;
          uint32_t pk = (uint32_t)(unsigned short)v0[j] |
                        ((uint32_t)(unsigned short)v1[j] << 16);
          *(uint32_t*)(vt + d * 144 + pcol) = pk;
        }
      }
      __syncthreads();
    }
  }

  if (half == 0) {  // blockA: raw qt_hi partial only
    write_partial();
    return;
  }
  // blockB: flush hi partial if the switch never triggered (nl == 0 case)
  if (!switched) {
    write_partial();
#pragma unroll
    for (int nd = 0; nd < 4; nd++) o[nd] = f32x4{0.f, 0.f, 0.f, 0.f};
    lrow = 0.f;
    cur_q0 = qt_lo * 64;
  }
  // blockB: normalized qt_lo output direct to acat
  float inv = lrow > 0.f ? 1.0f / lrow : 0.f;
#pragma unroll
  for (int jj = 0; jj < 4; jj++) {
    float iv = __shfl(inv, 4 * g + jj);
    size_t m = (size_t)(b * Tc + cur_q0 + w * 16 + g * 4 + jj);
#pragma unroll
    for (int nd = 0; nd < 4; nd++)
      acat[m * 1024 + h * 64 + nd * 16 + lr] = f2bf(o[nd][jj] * iv);
  }
}

// ---------------- combine: acat hi rows = (oA + oB) / (lA + lB) ----------------
__global__ __launch_bounds__(256) void k_combine(
    const float* __restrict__ o_slab, const float* __restrict__ l_slab,
    unsigned short* __restrict__ acat) {
  int i = blockIdx.x * 256 + threadIdx.x;  // over 2b x 1024row x 256 float4
  int c4 = i & 255;
  int row = (i >> 8) & 1023;
  int b = i >> 18;
  size_t i0 = ((size_t)b * 1024 + row) * 256 + c4;
  size_t i1 = ((size_t)(2 + b) * 1024 + row) * 256 + c4;
  float4 a = ((const float4*)o_slab)[i0];
  float4 c = ((const float4*)o_slab)[i1];
  int h = c4 >> 4;
  float l0 = l_slab[((size_t)b * 1024 + row) * 16 + h];
  float l1 = l_slab[((size_t)(2 + b) * 1024 + row) * 16 + h];
  float ls = l0 + l1;
  float inv = ls > 0.f ? 1.0f / ls : 0.f;
  uint2 out;
  out.x = cvt_pk_bf16((a.x + c.x) * inv, (a.y + c.y) * inv);
  out.y = cvt_pk_bf16((a.z + c.z) * inv, (a.w + c.w) * inv);
  ((uint2*)acat)[((size_t)b * 2048 + 1024 + row) * 256 + c4] = out;
}

extern "C" void kernel_launch(void* const* d_in, const int* in_sizes, int n_in,
                              void* d_out, int out_size, void* d_ws, size_t ws_size,
                              hipStream_t stream) {
  const float* x       = (const float*)d_in[0];
  const float* adj     = (const float*)d_in[1];
  const float* w_attn  = (const float*)d_in[2];
  const float* b_attn  = (const float*)d_in[3];
  const float* w_proj  = (const float*)d_in[4];
  const float* b_proj  = (const float*)d_in[5];
  const float* w_proj1 = (const float*)d_in[6];
  const float* b_proj1 = (const float*)d_in[7];
  float* out = (float*)d_out;

  char* ws = (char*)d_ws;
  size_t off = 0;
  unsigned short* xb     = (unsigned short*)(ws + off); off += (size_t)4096 * 1024 * 2;
  unsigned short* wattnT = (unsigned short*)(ws + off); off += (size_t)3072 * 1024 * 2;
  unsigned short* wcatT  = (unsigned short*)(ws + off); off += (size_t)1024 * 2048 * 2;
  unsigned short* qkv    = (unsigned short*)(ws + off); off += (size_t)4096 * 3072 * 2;
  unsigned short* acat   = (unsigned short*)(ws + off); off += (size_t)4096 * 1024 * 2;
  float*          o_slab = (float*)(ws + off);          off += (size_t)4 * 1024 * 1024 * 4;
  float*          l_slab = (float*)(ws + off);          off += (size_t)4 * 1024 * 16 * 4;
  unsigned char*  tmask  = (unsigned char*)(ws + off);  off += 1024;
  (void)ws_size; (void)in_sizes; (void)n_in; (void)out_size;

  // all prep in one dispatch (cvt_x | w_attn^T | w_proj^T | w_proj1^T*ln2 | tilemask)
  k_prep<<<10240, 256, 0, stream>>>(x, xb, w_attn, wattnT, w_proj, w_proj1, wcatT,
                                    adj, tmask);
  // qkv = x @ w_attn + b_attn (q columns scaled by log2e in epilogue)
  k_gemm0<<<dim3(24, 32), 256, 0, stream>>>(xb, 1024, wattnT, 1024, b_attn, qkv);
  // attention: 1024 balanced ~17-tile blocks; qt_hi partials to slabs, qt_lo direct
  k_attn<<<1024, 256, 0, stream>>>(qkv, adj, tmask, acat, o_slab, l_slab);
  // reduce the two qt_hi partials into acat (hi rows)
  k_combine<<<2048, 256, 0, stream>>>(o_slab, l_slab, acat);
  // out = [a | q*l2e] @ [w_proj ; w_proj1*ln2] + biases (M=64 tile, 512 blocks)
  k_gemm1<<<dim3(8, 64), 256, 0, stream>>>(acat, 1024, qkv, 3072,
                                           wcatT, b_proj, b_proj1, out);
}

// Round 16
// 125.207 us; speedup vs baseline: 1.1606x; 1.1606x over previous
//
#include <hip/hip_runtime.h>
#include <stdint.h>

typedef short s16x8 __attribute__((ext_vector_type(8)));
typedef float f32x4 __attribute__((ext_vector_type(4)));
typedef unsigned int u32x4 __attribute__((ext_vector_type(4)));

#define AS1 __attribute__((address_space(1)))
#define AS3 __attribute__((address_space(3)))

static constexpr int Bc = 2, Tc = 2048, NXc = 1024, Hc = 16;
static constexpr float NEGC = -1e9f;
static constexpr float L2E = 1.44269504088896340736f;  // log2(e)
static constexpr float LN2 = 0.69314718055994530942f;  // 1/log2(e)

static __device__ __forceinline__ unsigned short f2bf(float f) {
  uint32_t u = __builtin_bit_cast(uint32_t, f);
  u += 0x7fffu + ((u >> 16) & 1u);
  return (unsigned short)(u >> 16);
}

static __device__ __forceinline__ float exp2fast(float x) {
  return __builtin_amdgcn_exp2f(x);  // v_exp_f32: D = 2^S0
}

static __device__ __forceinline__ uint32_t cvt_pk_bf16(float lo, float hi) {
  uint32_t r;
  asm("v_cvt_pk_bf16_f32 %0, %1, %2" : "=v"(r) : "v"(lo), "v"(hi));
  return r;
}

static __device__ __forceinline__ void gload_lds16(const void* g, void* l) {
  __builtin_amdgcn_global_load_lds((const AS1 uint32_t*)g, (AS3 uint32_t*)l, 16, 0, 0);
}

// ---------------- fused prep: cvt_x | 3 transposes | tilemask(64x64) ----------------
__global__ __launch_bounds__(256) void k_prep(
    const float* __restrict__ x, unsigned short* __restrict__ xb,
    const float* __restrict__ w_attn, unsigned short* __restrict__ wattnT,
    const float* __restrict__ w_proj, const float* __restrict__ w_proj1,
    unsigned short* __restrict__ wcatT,
    const float* __restrict__ adj, unsigned char* __restrict__ tm) {
  __shared__ float tile[32][33];
  __shared__ int s_any, s_all;
  const int bid = blockIdx.x;
  const int t = threadIdx.x;

  if (bid < 4096) {  // x -> bf16
    int i = bid * 256 + t;
    float4 v = ((const float4*)x)[i];
    uint32_t lo = (uint32_t)f2bf(v.x) | ((uint32_t)f2bf(v.y) << 16);
    uint32_t hi = (uint32_t)f2bf(v.z) | ((uint32_t)f2bf(v.w) << 16);
    ((uint2*)xb)[i] = make_uint2(lo, hi);
    return;
  }
  if (bid < 9216) {  // f32 [K][N] -> bf16 [N][dld] transposes
    const float* src; unsigned short* dst;
    int scols, dld, dkoff, n0, k0; float scale;
    if (bid < 7168) {
      int b = bid - 4096; n0 = (b % 96) * 32; k0 = (b / 96) * 32;
      src = w_attn; scols = 3072; dst = wattnT; dld = 1024; dkoff = 0; scale = 1.0f;
    } else if (bid < 8192) {
      int b = bid - 7168; n0 = (b & 31) * 32; k0 = (b >> 5) * 32;
      src = w_proj; scols = 1024; dst = wcatT; dld = 2048; dkoff = 0; scale = 1.0f;
    } else {
      int b = bid - 8192; n0 = (b & 31) * 32; k0 = (b >> 5) * 32;
      // w_proj1 pre-scaled by ln2 cancels the log2e baked into q (exp2 rebasing)
      src = w_proj1; scols = 1024; dst = wcatT; dld = 2048; dkoff = 1024; scale = LN2;
    }
    int tx = t & 31, ty = t >> 5;
#pragma unroll
    for (int r = 0; r < 4; r++)
      tile[ty + r * 8][tx] = src[(size_t)(k0 + ty + r * 8) * scols + n0 + tx];
    __syncthreads();
#pragma unroll
    for (int r = 0; r < 4; r++) {
      int n = n0 + ty + r * 8;
      dst[(size_t)n * dld + dkoff + k0 + tx] = f2bf(tile[tx][ty + r * 8] * scale);
    }
    return;
  }
  {  // adjacency 64x64 tile classifier: 0=skip, 1=mixed, 2=all-ones
    int b = bid - 9216;
    int kt = b & 31, qt = b >> 5;
    bool anyv = false, all1 = true;
#pragma unroll
    for (int i = 0; i < 4; i++) {
      int e = t * 4 + i;
      int row = e >> 4, c4 = e & 15;
      float4 v = *(const float4*)&adj[(size_t)(qt * 64 + row) * Tc + kt * 64 + c4 * 4];
      anyv |= (v.x != 0.f) | (v.y != 0.f) | (v.z != 0.f) | (v.w != 0.f);
      all1 &= (v.x == 1.f) & (v.y == 1.f) & (v.z == 1.f) & (v.w == 1.f);
    }
    if (t == 0) { s_any = 0; s_all = 1; }
    __syncthreads();
    if (anyv) s_any = 1;
    if (!all1) s_all = 0;
    __syncthreads();
    if (t == 0) tm[qt * 32 + kt] = (unsigned char)(s_any ? (s_all ? 2 : 1) : 0);
  }
}

// ---------------- GEMM0: qkv = xb @ wattnT^T + b_attn (m97-structure, BK=32) ------
__global__ __launch_bounds__(256) void k_gemm0(
    const unsigned short* __restrict__ A, int lda,
    const unsigned short* __restrict__ BT, int K,
    const float* __restrict__ bias0, unsigned short* __restrict__ Cb) {
  __shared__ __align__(16) unsigned short As[128 * 32];
  __shared__ __align__(16) unsigned short Bs[128 * 32];
  const int nbx = gridDim.x, nby = gridDim.y;
  const int nwg = nbx * nby;
  int id = blockIdx.y * nbx + blockIdx.x;
  id = (id & 7) * (nwg >> 3) + (id >> 3);  // T1 XCD swizzle (nwg % 8 == 0)
  const int bx = id % nbx;
  const int by = id / nbx;
  const int m0 = by * 128;
  const int n0 = bx * 128;

  const int lane = threadIdx.x & 63;
  const int w = threadIdx.x >> 6;
  const int wr = (w >> 1) * 64;
  const int wc = (w & 1) * 64;
  const int g = lane >> 4, lr = lane & 15;
  const int srow = lane >> 2;
  const int scol = lane & 3;
  f32x4 acc[4][4] = {};

  for (int k0 = 0; k0 < K; k0 += 32) {
    __syncthreads();
#pragma unroll
    for (int i = 0; i < 2; i++) {
      int c = w * 2 + i;
      int row = c * 16 + srow;
      int cs = scol ^ (row & 3);
      gload_lds16(A + (size_t)(m0 + row) * lda + k0 + cs * 8, (void*)(As + c * 512));
      gload_lds16(BT + (size_t)(n0 + row) * K + k0 + cs * 8, (void*)(Bs + c * 512));
    }
    __syncthreads();
    s16x8 af[4], bfr[4];
#pragma unroll
    for (int m = 0; m < 4; m++) {
      int row = wr + m * 16 + lr;
      af[m] = *(const s16x8*)((const char*)As + row * 64 + ((g ^ (row & 3)) * 16));
    }
#pragma unroll
    for (int n = 0; n < 4; n++) {
      int row = wc + n * 16 + lr;
      bfr[n] = *(const s16x8*)((const char*)Bs + row * 64 + ((g ^ (row & 3)) * 16));
    }
#pragma unroll
    for (int m = 0; m < 4; m++)
#pragma unroll
      for (int n = 0; n < 4; n++)
        acc[m][n] = __builtin_amdgcn_mfma_f32_16x16x32_bf16(af[m], bfr[n], acc[m][n], 0, 0, 0);
  }

#pragma unroll
  for (int m = 0; m < 4; m++) {
    int row = m0 + wr + m * 16 + g * 4;
#pragma unroll
    for (int n = 0; n < 4; n++) {
      int col = n0 + wc + n * 16 + lr;
      float bs = bias0[col];
      float sc = (col < NXc) ? L2E : 1.0f;  // pre-scale q for exp2-softmax
#pragma unroll
      for (int jj = 0; jj < 4; jj++)
        Cb[(size_t)(row + jj) * 3072 + col] = f2bf((acc[m][n][jj] + bs) * sc);
    }
  }
}

// ---------------- GEMM1: out = [acat | q] @ wcatT^T + biases (M=64 tile, dbuf) -------
__global__ __launch_bounds__(256) void k_gemm1(
    const unsigned short* __restrict__ A, int lda,    // acat (k < 1024)
    const unsigned short* __restrict__ A2, int lda2,  // qkv cols 0..1023 (k >= 1024)
    const unsigned short* __restrict__ BT,            // [1024][2048]
    const float* __restrict__ bias0, const float* __restrict__ bias1,
    float* __restrict__ Cf) {
  constexpr int K = 2048, ksplit = 1024;
  __shared__ __align__(16) unsigned short As[2][64 * 32];    // 8 KB dbuf
  __shared__ __align__(16) unsigned short Bs[2][128 * 32];   // 16 KB dbuf
  const int nbx = gridDim.x, nby = gridDim.y;
  const int nwg = nbx * nby;
  int id = blockIdx.y * nbx + blockIdx.x;
  id = (id & 7) * (nwg >> 3) + (id >> 3);  // T1 XCD swizzle (512 % 8 == 0)
  const int bx = id % nbx;
  const int by = id / nbx;
  const int m0 = by * 64;
  const int n0 = bx * 128;

  const int tid = threadIdx.x;
  const int lane = tid & 63;
  const int w = tid >> 6;
  const int wr = (w >> 1) * 32;
  const int wc = (w & 1) * 64;
  const int g = lane >> 4, lr = lane & 15;
  const int srow = lane >> 2;
  const int scol = lane & 3;
  const int arow = tid >> 2;
  f32x4 acc[2][4] = {};

  auto stage = [&](int k0, int buf) {
    {
      int acs = (tid & 3) ^ (arow & 3);
      const unsigned short* ap = (k0 < ksplit)
          ? A + (size_t)(m0 + arow) * lda + k0
          : A2 + (size_t)(m0 + arow) * lda2 + (k0 - ksplit);
      gload_lds16(ap + acs * 8, (void*)(&As[buf][0] + w * 512));
    }
#pragma unroll
    for (int i = 0; i < 2; i++) {
      int c = w * 2 + i;
      int row = c * 16 + srow;
      int cs = scol ^ (row & 3);
      gload_lds16(BT + (size_t)(n0 + row) * K + k0 + cs * 8, (void*)(&Bs[buf][0] + c * 512));
    }
  };

  stage(0, 0);
  __syncthreads();

  for (int k0 = 0; k0 < K; k0 += 32) {
    const int cur = (k0 >> 5) & 1;
    if (k0 + 32 < K) stage(k0 + 32, cur ^ 1);
    s16x8 af[2], bfr[4];
#pragma unroll
    for (int m = 0; m < 2; m++) {
      int row = wr + m * 16 + lr;
      af[m] = *(const s16x8*)((const char*)&As[cur][0] + row * 64 + ((g ^ (row & 3)) * 16));
    }
#pragma unroll
    for (int n = 0; n < 4; n++) {
      int row = wc + n * 16 + lr;
      bfr[n] = *(const s16x8*)((const char*)&Bs[cur][0] + row * 64 + ((g ^ (row & 3)) * 16));
    }
#pragma unroll
    for (int m = 0; m < 2; m++)
#pragma unroll
      for (int n = 0; n < 4; n++)
        acc[m][n] = __builtin_amdgcn_mfma_f32_16x16x32_bf16(af[m], bfr[n], acc[m][n], 0, 0, 0);
    __syncthreads();
  }

#pragma unroll
  for (int m = 0; m < 2; m++) {
    int row = m0 + wr + m * 16 + g * 4;
#pragma unroll
    for (int n = 0; n < 4; n++) {
      int col = n0 + wc + n * 16 + lr;
      float bs = bias0[col] + bias1[col];
#pragma unroll
      for (int jj = 0; jj < 4; jj++)
        Cf[(size_t)(row + jj) * NXc + col] = acc[m][n][jj] + bs;
    }
  }
}

// ---------------- flash attention v11: 2-deep register-staged K/V pipeline ----------
// r15 lesson: runtime is NOT chain-bound; it's memory latency exposed at the barrier.
// Root cause: global_load_lds prefetch is force-drained by the vmcnt(0) the compiler
// emits before every __syncthreads — cover = ONE tile's compute. Fix: K staged via
// registers (same pre-swizzled global addresses, linear ds_write_b128 to the same LDS
// offsets -> byte-identical K image), pipeline 2 tiles deep: iter i writes tile i+1's
// regs to LDS (vmcnt wait lands HERE), issues tile i+2 loads (regs - no barrier
// drain), computes tile i. Sync structure unchanged: one __syncthreads per tile.
__global__ __launch_bounds__(256) void k_attn(
    const unsigned short* __restrict__ qkv,  // [4096][3072] bf16 (q*l2e | k | v)
    const float* __restrict__ adj,           // [2048][2048]
    const unsigned char* __restrict__ tm,    // [32][32] 64x64 tiles
    unsigned short* __restrict__ acat) {     // [4096][1024] bf16
  __shared__ __align__(16) unsigned short Kb[2][64 * 64];   // [kv][16B-gran ^ (kv&7)]
  __shared__ __align__(16) unsigned short Vt[2][64 * 72];   // row d: sigma-permuted kv
  __shared__ int s_kts[34];
  __shared__ unsigned char s_tmv[32];
  __shared__ int s_nkt;

  const int bid = blockIdx.x;
  const int qt = 31 - (bid >> 5);  // heavy-first
  const int bh = bid & 31;
  const int h = bh & 15;
  const int b = bh >> 4;
  const int q0 = qt * 64;
  const int tid = threadIdx.x;
  const int lane = tid & 63;
  const int w = tid >> 6;
  const int g = lane >> 4, lr = lane & 15;
  const int sc = tid & 7;
  const int sr = tid >> 3;  // 0..31
  const int kvp = 2 * sr;
  const int prp = (kvp & 32) | (((kvp >> 4) & 1) << 2) | ((kvp & 12) << 1) | (kvp & 3);

  // wave-parallel compacted active-tile list (clamped at [n] and [n+1] for 2-deep)
  if (w == 0) {
    int kt = lane & 31;
    unsigned char v = tm[qt * 32 + kt];
    bool act = (lane < 32) && (v != 0);
    unsigned long long mk = __ballot(act);
    int n = __popcll(mk);
    if (act) {
      int idx = __popcll(mk & ((1ull << lane) - 1));
      s_kts[idx] = kt;
      s_tmv[idx] = v;
      if (idx == n - 1) { s_kts[n] = kt; s_kts[n + 1] = kt; }
    }
    if (lane == 0) s_nkt = n;
  }

  // Q fragments (mfma B-operand: col=q=lr, k=8g+j)
  s16x8 qf0, qf1;
  {
    size_t base = (size_t)(b * Tc + q0 + w * 16 + lr) * 3072 + h * 64 + g * 8;
    qf0 = *(const s16x8*)(qkv + base);
    qf1 = *(const s16x8*)(qkv + base + 32);
  }
  f32x4 o[4] = {};
  float lrow = 0.f;

  __syncthreads();  // s_kts visible
  const int nkt = s_nkt;
  if (nkt == 0) return;  // block-uniform

  const unsigned short* kbase = qkv + (size_t)(b * Tc) * 3072 + 1024 + h * 64;
  const unsigned short* vbase = kbase + 1024;

  // staging addresses: K source pre-swizzled (G21), K dest LINEAR (byte-identical
  // image to the old global_load_lds path); V^T sigma-permuted paired writes.
  const size_t koff0 = (size_t)sr * 3072 + (sc ^ (sr & 7)) * 8;
  const size_t koff1 = (size_t)(sr + 32) * 3072 + (sc ^ (sr & 7)) * 8;
  const int kd0 = w * 1024 + lane * 16;   // bytes
  const int kd1 = kd0 + 4096;
  const size_t voff0 = (size_t)kvp * 3072 + sc * 8;
  const size_t voff1 = (size_t)(kvp + 1) * 3072 + sc * 8;
  const int pcol = ((prp + sc * 8) & 63) * 2;

  s16x8 kA0, kA1, vA0, vA1;  // in-flight staging registers (one set, 2-deep pipeline)
  auto load_tile = [&](int kt) {
    const unsigned short* kb = kbase + (size_t)kt * 64 * 3072;
    const unsigned short* vb = vbase + (size_t)kt * 64 * 3072;
    kA0 = *(const s16x8*)(kb + koff0);
    kA1 = *(const s16x8*)(kb + koff1);
    vA0 = *(const s16x8*)(vb + voff0);
    vA1 = *(const s16x8*)(vb + voff1);
  };
  auto write_tile = [&](int buf) {
    *(s16x8*)((char*)&Kb[buf][0] + kd0) = kA0;
    *(s16x8*)((char*)&Kb[buf][0] + kd1) = kA1;
    char* vt = (char*)&Vt[buf][0];
#pragma unroll
    for (int j = 0; j < 8; j++) {
      int d = sc * 8 + j;
      uint32_t pk = (uint32_t)(unsigned short)vA0[j] |
                    ((uint32_t)(unsigned short)vA1[j] << 16);
      *(uint32_t*)(vt + d * 144 + pcol) = pk;
    }
  };

  // prologue: tile 0 -> LDS buf0; tile 1 loads left in flight (registers)
  load_tile(s_kts[0]);
  write_tile(0);
  load_tile(s_kts[1]);
  __syncthreads();  // drains ds_writes (lgkm); reg loads keep flying across barrier

  for (int i = 0; i < nkt; i++) {
    const int cur = i & 1;
    const int kt = s_kts[i];
    const int tmv = s_tmv[i];
    const int kv0 = kt * 64;

    // (1) write tile i+1 into buf^1 (vmcnt wait for its loads lands here — they have
    //     had a full iteration to complete); barrier at end of i-1 fenced readers.
    write_tile(cur ^ 1);
    // (2) issue tile i+2 loads into the freed registers
    load_tile(s_kts[i + 2]);

    // (3) compute tile i
    f32x4 s[4];
    __builtin_amdgcn_s_setprio(1);
#pragma unroll
    for (int n = 0; n < 4; n++) {
      int kvr = n * 16 + lr;
      const char* kr = (const char*)&Kb[cur][0] + kvr * 128;
      s16x8 a0 = *(const s16x8*)(kr + ((g ^ (kvr & 7)) * 16));
      s16x8 a1 = *(const s16x8*)(kr + (((4 + g) ^ (kvr & 7)) * 16));
      f32x4 z = {};
      z = __builtin_amdgcn_mfma_f32_16x16x32_bf16(a0, qf0, z, 0, 0, 0);
      s[n] = __builtin_amdgcn_mfma_f32_16x16x32_bf16(a1, qf1, z, 0, 0, 0);
    }
    __builtin_amdgcn_s_setprio(0);

    if (tmv != 2) {  // w = s*adj + NEG*(1-adj), exact for binary adj
      const float* arow = adj + (size_t)(q0 + w * 16 + lr) * Tc + kv0;
#pragma unroll
      for (int n = 0; n < 4; n++) {
        float4 a = *(const float4*)(arow + n * 16 + 4 * g);
        s[n][0] = a.x * s[n][0] + NEGC * (1.0f - a.x);
        s[n][1] = a.y * s[n][1] + NEGC * (1.0f - a.y);
        s[n][2] = a.z * s[n][2] + NEGC * (1.0f - a.z);
        s[n][3] = a.w * s[n][3] + NEGC * (1.0f - a.w);
      }
    }

    // ---- no-max softmax: P = exp2(s) directly (s pre-scaled by log2e) ----
    float ps0 = 0.f, ps1 = 0.f;
#pragma unroll
    for (int n = 0; n < 4; n++) {
      float p0 = exp2fast(s[n][0]), p1 = exp2fast(s[n][1]);
      float p2 = exp2fast(s[n][2]), p3 = exp2fast(s[n][3]);
      s[n][0] = p0; s[n][1] = p1; s[n][2] = p2; s[n][3] = p3;
      ps0 += (p0 + p1); ps1 += (p2 + p3);
    }
    float ps = ps0 + ps1;
    ps += __shfl_xor(ps, 16);
    ps += __shfl_xor(ps, 32);
    lrow += ps;

    // ---- P stays in registers: sigma-renamed packs (no LDS roundtrip) ----
    u32x4 pw0, pw1;
    pw0.x = cvt_pk_bf16(s[0][0], s[0][1]);
    pw0.y = cvt_pk_bf16(s[0][2], s[0][3]);
    pw0.z = cvt_pk_bf16(s[1][0], s[1][1]);
    pw0.w = cvt_pk_bf16(s[1][2], s[1][3]);
    pw1.x = cvt_pk_bf16(s[2][0], s[2][1]);
    pw1.y = cvt_pk_bf16(s[2][2], s[2][3]);
    pw1.z = cvt_pk_bf16(s[3][0], s[3][1]);
    pw1.w = cvt_pk_bf16(s[3][2], s[3][3]);
    s16x8 pa0 = __builtin_bit_cast(s16x8, pw0);
    s16x8 pa1 = __builtin_bit_cast(s16x8, pw1);

    __builtin_amdgcn_s_setprio(1);
#pragma unroll
    for (int nd = 0; nd < 4; nd++) {
      int d = nd * 16 + lr;
      const char* vrow = (const char*)&Vt[cur][0] + d * 144;
      int swz = (d >> 3) * 8;
      s16x8 vb0 = *(const s16x8*)(vrow + (((8 * g + swz) & 63) * 2));
      s16x8 vb1 = *(const s16x8*)(vrow + (((32 + 8 * g + swz) & 63) * 2));
      o[nd] = __builtin_amdgcn_mfma_f32_16x16x32_bf16(pa0, vb0, o[nd], 0, 0, 0);
      o[nd] = __builtin_amdgcn_mfma_f32_16x16x32_bf16(pa1, vb1, o[nd], 0, 0, 0);
    }
    __builtin_amdgcn_s_setprio(0);

    __syncthreads();  // single barrier/tile: publishes buf^1, fences cur reuse
  }

  float inv = lrow > 0.f ? 1.0f / lrow : 0.f;
#pragma unroll
  for (int jj = 0; jj < 4; jj++) {
    float iv = __shfl(inv, 4 * g + jj);
    size_t m = (size_t)(b * Tc + q0 + w * 16 + g * 4 + jj);
#pragma unroll
    for (int nd = 0; nd < 4; nd++)
      acat[m * 1024 + h * 64 + nd * 16 + lr] = f2bf(o[nd][jj] * iv);
  }
}

extern "C" void kernel_launch(void* const* d_in, const int* in_sizes, int n_in,
                              void* d_out, int out_size, void* d_ws, size_t ws_size,
                              hipStream_t stream) {
  const float* x       = (const float*)d_in[0];
  const float* adj     = (const float*)d_in[1];
  const float* w_attn  = (const float*)d_in[2];
  const float* b_attn  = (const float*)d_in[3];
  const float* w_proj  = (const float*)d_in[4];
  const float* b_proj  = (const float*)d_in[5];
  const float* w_proj1 = (const float*)d_in[6];
  const float* b_proj1 = (const float*)d_in[7];
  float* out = (float*)d_out;

  char* ws = (char*)d_ws;
  size_t off = 0;
  unsigned short* xb     = (unsigned short*)(ws + off); off += (size_t)4096 * 1024 * 2;
  unsigned short* wattnT = (unsigned short*)(ws + off); off += (size_t)3072 * 1024 * 2;
  unsigned short* wcatT  = (unsigned short*)(ws + off); off += (size_t)1024 * 2048 * 2;
  unsigned short* qkv    = (unsigned short*)(ws + off); off += (size_t)4096 * 3072 * 2;
  unsigned short* acat   = (unsigned short*)(ws + off); off += (size_t)4096 * 1024 * 2;
  unsigned char*  tmask  = (unsigned char*)(ws + off);  off += 1024;
  (void)ws_size; (void)in_sizes; (void)n_in; (void)out_size;

  // all prep in one dispatch (cvt_x | w_attn^T | w_proj^T | w_proj1^T*ln2 | tilemask)
  k_prep<<<10240, 256, 0, stream>>>(x, xb, w_attn, wattnT, w_proj, w_proj1, wcatT,
                                    adj, tmask);
  // qkv = x @ w_attn + b_attn (q columns scaled by log2e in epilogue)
  k_gemm0<<<dim3(24, 32), 256, 0, stream>>>(xb, 1024, wattnT, 1024, b_attn, qkv);
  // attention -> acat [4096][1024]
  k_attn<<<1024, 256, 0, stream>>>(qkv, adj, tmask, acat);
  // out = [a | q*l2e] @ [w_proj ; w_proj1*ln2] + biases (M=64 tile, 512 blocks)
  k_gemm1<<<dim3(8, 64), 256, 0, stream>>>(acat, 1024, qkv, 3072,
                                           wcatT, b_proj, b_proj1, out);
}